// Round 7
// baseline (230.391 us; speedup 1.0000x reference)
//
#include <hip/hip_runtime.h>
#include <hip/hip_fp8.h>
#include <math.h>

#define TAU 32.0f
#define LO_SCALE 2048.0f
#define INV_LO_SCALE (1.0f/2048.0f)

typedef _Float16 f16x8 __attribute__((ext_vector_type(8)));
typedef float    f32x16 __attribute__((ext_vector_type(16)));

#if defined(__has_builtin)
#if __has_builtin(__builtin_amdgcn_cvt_f32_fp8) && __has_builtin(__builtin_amdgcn_cvt_pk_fp8_f32)
#define HAVE_FP8_BUILTINS 1
#endif
#endif

static __device__ __forceinline__ unsigned char enc_e4m3(float x) {
#ifdef HAVE_FP8_BUILTINS
    int p = __builtin_amdgcn_cvt_pk_fp8_f32(x, x, 0, false);
    return (unsigned char)(p & 0xff);
#else
    __hip_fp8_e4m3 q(x);
    return (unsigned char)q.__x;
#endif
}

#ifdef HAVE_FP8_BUILTINS
#define DEC_E4M3(W, SEL) __builtin_amdgcn_cvt_f32_fp8((int)(W), (SEL))
#else
static __device__ __forceinline__ float dec_e4m3_sw(unsigned w, int sel) {
    __hip_fp8_e4m3 q; q.__x = (unsigned char)((w >> (8 * sel)) & 0xff);
    return (float)q;
}
#define DEC_E4M3(W, SEL) dec_e4m3_sw((W), (SEL))
#endif

// ---------------------------------------------------------------------------
// Kernel 1: MW[n][k] = sum_e M[n%90][e] * W[e][k]  (n<90: W_topic, 90<=n<180:
// W_domain, 180..191: zero pad), written in PACKED MFMA-FRAGMENT ORDER:
//   frag = (k/16)*6 + n/32 ; within frag: lane = ((k>>3)&1)*32 + (n&31), j=k&7
//   PBhi[frag*512 + lane*8 + j] (f16), PBlo[...] (e4m3 of lo*2048)
// -> fused kernel's B loads become 1KB fully-coalesced streams (round 5/6 were
//    1536B-strided scatters, ~32 cache lines/load = the measured bottleneck).
// Total ws: 192*768*2B + 192*768*1B = 442,368 B (fits proven 552,960).
// ---------------------------------------------------------------------------
__global__ __launch_bounds__(256) void precompute_mw_packed(
    const float* __restrict__ Wt, const float* __restrict__ Wd,
    const float* __restrict__ dmem, _Float16* __restrict__ PBhi,
    unsigned char* __restrict__ PBlo)
{
    __shared__ float Ml[3 * 768];
    const int nt = blockIdx.x;    // 0..63 -> rows 3nt..3nt+2 of 192
    const int kc = blockIdx.y;    // 0..2
    const int n0 = nt * 3;
    const int k  = kc * 256 + threadIdx.x;
    float v[3] = {0.f, 0.f, 0.f};
    if (n0 < 180) {               // block-uniform branch (sync inside is safe)
        const float* __restrict__ W = (n0 < 90) ? Wt : Wd;
        const int m0 = (n0 < 90) ? n0 : n0 - 90;
        for (int idx = threadIdx.x; idx < 3 * 768; idx += 256)
            Ml[idx] = dmem[m0 * 768 + idx];
        __syncthreads();
        float a0 = 0.f, a1 = 0.f, a2 = 0.f;
        #pragma unroll 16
        for (int e = 0; e < 768; ++e) {
            const float w = W[e * 768 + k];
            a0 = fmaf(Ml[e],        w, a0);
            a1 = fmaf(Ml[768 + e],  w, a1);
            a2 = fmaf(Ml[1536 + e], w, a2);
        }
        v[0] = a0; v[1] = a1; v[2] = a2;
    }
    const int t = k >> 5, ks = (k >> 4) & 1, h = (k >> 3) & 1, j = k & 7;
    const int fragc = (t * 2 + ks) * 6;
    #pragma unroll
    for (int i = 0; i < 3; ++i) {
        const int n = n0 + i;
        const int idx = (fragc + (n >> 5)) * 512 + (h * 32 + (n & 31)) * 8 + j;
        _Float16 hi = (_Float16)v[i];
        float lo = (v[i] - (float)hi) * LO_SCALE;
        PBhi[idx] = hi;
        PBlo[idx] = enc_e4m3(lo);
    }
}

// ---------------------------------------------------------------------------
// Kernel 2: split-precision MFMA GEMM (f16 hi/hi + cross terms w/ fp8 B-lo)
// + fused softmax chain. Round-5 structure (single A buffer, 58.6 KB LDS,
// 2 blocks/CU) + packed coalesced B + 1-ksub-deep B ping-pong prefetch.
// ---------------------------------------------------------------------------
#define MFMA_BODY(KS, BH, BL) do {                                          \
    const int _ao = (arow * 64 + (KS) * 32 + asel) ^ swzA;                  \
    f16x8 _ah = *(const f16x8*)((const char*)AhL + _ao);                    \
    f16x8 _al = *(const f16x8*)((const char*)AlL + _ao);                    \
    _Pragma("unroll")                                                       \
    for (int _nt = 0; _nt < 3; ++_nt) {                                     \
        f16x8 _bl;                                                          \
        _bl[0] = (_Float16)DEC_E4M3(BL[_nt].x, 0);                          \
        _bl[1] = (_Float16)DEC_E4M3(BL[_nt].x, 1);                          \
        _bl[2] = (_Float16)DEC_E4M3(BL[_nt].x, 2);                          \
        _bl[3] = (_Float16)DEC_E4M3(BL[_nt].x, 3);                          \
        _bl[4] = (_Float16)DEC_E4M3(BL[_nt].y, 0);                          \
        _bl[5] = (_Float16)DEC_E4M3(BL[_nt].y, 1);                          \
        _bl[6] = (_Float16)DEC_E4M3(BL[_nt].y, 2);                          \
        _bl[7] = (_Float16)DEC_E4M3(BL[_nt].y, 3);                          \
        acc1[_nt] = __builtin_amdgcn_mfma_f32_32x32x16_f16(_ah, BH[_nt], acc1[_nt], 0, 0, 0); \
        acc2[_nt] = __builtin_amdgcn_mfma_f32_32x32x16_f16(_ah, _bl,     acc2[_nt], 0, 0, 0); \
        acc2[_nt] = __builtin_amdgcn_mfma_f32_32x32x16_f16(_al, BH[_nt], acc2[_nt], 0, 0, 0); \
    }                                                                       \
} while (0)

__global__ __launch_bounds__(256, 1) void fused_memnet(
    const float* __restrict__ F, const _Float16* __restrict__ PBhi,
    const unsigned char* __restrict__ PBlo, float* __restrict__ out)
{
    __shared__ alignas(16) _Float16 AhL[64 * 32];   // 4 KB swizzled
    __shared__ alignas(16) _Float16 AlL[64 * 32];   // 4 KB
    __shared__ float raw[64 * 196];                 // 50.2 KB epilogue
    __shared__ float ss[64];

    const int tid  = threadIdx.x;
    const int lane = tid & 63;
    const int wid  = tid >> 6;
    const int wrow = (wid >> 1) * 32;
    const int wcol = (wid & 1) * 96;
    const int row0 = blockIdx.x * 64;

    // A staging ids
    const int srow = tid >> 2;
    const int sc   = tid & 3;
    const float* __restrict__ Fp = F + (row0 + srow) * 768 + sc * 8;
    const int wb = (srow * 64 + sc * 16) ^ ((srow & 7) << 4);

    // packed-B per-lane bases (coalesced: 64 lanes x 16B hi / 8B lo contiguous)
    const _Float16*      __restrict__ pbh = PBhi + (wid & 1) * 3 * 512 + lane * 8;
    const unsigned char* __restrict__ pbl = PBlo + (wid & 1) * 3 * 512 + lane * 8;

    // A fragment read addressing
    const int arow = wrow + (lane & 31);
    const int swzA = (arow & 7) << 4;
    const int asel = (lane >> 5) * 16;

    f32x16 acc1[3], acc2[3];
    #pragma unroll
    for (int nt = 0; nt < 3; ++nt)
        #pragma unroll
        for (int r = 0; r < 16; ++r) { acc1[nt][r] = 0.f; acc2[nt][r] = 0.f; }

    float ps = 0.f;
    float4 p0 = *(const float4*)(Fp);
    float4 p1 = *(const float4*)(Fp + 4);

    f16x8 Bh0[3], Bh1[3];
    uint2 Bl0[3], Bl1[3];
    #pragma unroll
    for (int nt = 0; nt < 3; ++nt) {            // preload ksub_lin = 0
        Bh0[nt] = *(const f16x8*)(pbh + nt * 512);
        Bl0[nt] = *(const uint2*)(pbl + nt * 512);
    }

    for (int t = 0; t < 24; ++t) {
        __syncthreads();                        // window t-1 LDS reads done
        {   // convert & store A window t, accumulate sumsq
            f16x8 h8, l8;
            float xs[8] = {p0.x, p0.y, p0.z, p0.w, p1.x, p1.y, p1.z, p1.w};
            #pragma unroll
            for (int i = 0; i < 8; ++i) {
                float x = xs[i];
                _Float16 hh = (_Float16)x;
                h8[i] = hh;
                l8[i] = (_Float16)((x - (float)hh) * LO_SCALE);
                ps += x * x;
            }
            *(f16x8*)((char*)AhL + wb) = h8;
            *(f16x8*)((char*)AlL + wb) = l8;
        }
        if (t < 23) {                           // F prefetch (1 window deep)
            p0 = *(const float4*)(Fp + (t + 1) * 32);
            p1 = *(const float4*)(Fp + (t + 1) * 32 + 4);
        }
        __syncthreads();                        // window t A visible

        // ksub 0 (kl=2t): prefetch kl=2t+1 into slot1, MFMA slot0
        #pragma unroll
        for (int nt = 0; nt < 3; ++nt) {
            Bh1[nt] = *(const f16x8*)(pbh + (2 * t + 1) * 3072 + nt * 512);
            Bl1[nt] = *(const uint2*)(pbl + (2 * t + 1) * 3072 + nt * 512);
        }
        MFMA_BODY(0, Bh0, Bl0);
        // ksub 1 (kl=2t+1): prefetch kl=2t+2 into slot0, MFMA slot1
        if (t < 23) {
            #pragma unroll
            for (int nt = 0; nt < 3; ++nt) {
                Bh0[nt] = *(const f16x8*)(pbh + (2 * t + 2) * 3072 + nt * 512);
                Bl0[nt] = *(const uint2*)(pbl + (2 * t + 2) * 3072 + nt * 512);
            }
        }
        MFMA_BODY(1, Bh1, Bl1);
    }

    // ---- row sum-of-squares: 4 staging threads per row
    ps += __shfl_xor(ps, 1);
    ps += __shfl_xor(ps, 2);
    if (sc == 0) ss[srow] = ps;

    // ---- write raw scores (verified 32x32 C/D layout:
    //      col=lane&31, row=(reg&3)+8*(reg>>2)+4*(lane>>5))
    #pragma unroll
    for (int nt = 0; nt < 3; ++nt) {
        const int cl = wcol + nt * 32 + (lane & 31);
        #pragma unroll
        for (int r = 0; r < 16; ++r) {
            const int rl = wrow + (r & 3) + 8 * (r >> 2) + 4 * (lane >> 5);
            raw[rl * 196 + cl] = acc1[nt][r] + acc2[nt][r] * INV_LO_SCALE;
        }
    }
    __syncthreads();

    // ---- softmax chain, one thread per row
    if (tid < 64) {
        const int r = tid;
        const float s = TAU / sqrtf(ss[r]);       // TAU / ||f||
        const float* Sr = raw + r * 196;
        float logit[9];
        #pragma unroll
        for (int d = 0; d < 9; ++d) {
            float vv[10];
            float mx = -1e30f;
            #pragma unroll
            for (int m = 0; m < 10; ++m) {
                vv[m] = s * Sr[d * 10 + m];
                mx = fmaxf(mx, vv[m]);
            }
            float den = 0.f, num = 0.f;
            #pragma unroll
            for (int m = 0; m < 10; ++m) {
                const float e = expf(vv[m] - mx);
                den += e;
                num = fmaf(e, Sr[90 + d * 10 + m], num);
            }
            logit[d] = s * num / den;             // TAU * (sep_emb . q_dom)
        }
        float mx2 = -1e30f;
        #pragma unroll
        for (int d = 0; d < 9; ++d) mx2 = fmaxf(mx2, logit[d]);
        float e2[9], den2 = 0.f;
        #pragma unroll
        for (int d = 0; d < 9; ++d) { e2[d] = expf(logit[d] - mx2); den2 += e2[d]; }
        const float inv = 1.f / den2;
        float* op = out + (row0 + r) * 9;
        #pragma unroll
        for (int d = 0; d < 9; ++d) op[d] = e2[d] * inv;
    }
}

// ---------------------------------------------------------------------------
extern "C" void kernel_launch(void* const* d_in, const int* in_sizes, int n_in,
                              void* d_out, int out_size, void* d_ws, size_t ws_size,
                              hipStream_t stream)
{
    const float* feature = (const float*)d_in[0];
    // d_in[1] = category (int64) — unused by the reference computation
    const float* Wt   = (const float*)d_in[2];
    const float* Wd   = (const float*)d_in[3];
    const float* dmem = (const float*)d_in[4];
    float* outp = (float*)d_out;
    _Float16* PBhi = (_Float16*)d_ws;                           // 294,912 B
    unsigned char* PBlo = (unsigned char*)d_ws + 192 * 768 * 2; // 147,456 B

    precompute_mw_packed<<<dim3(64, 3), 256, 0, stream>>>(Wt, Wd, dmem, PBhi, PBlo);
    fused_memnet<<<32768 / 64, 256, 0, stream>>>(feature, PBhi, PBlo, outp);
}

// Round 8
// 106.864 us; speedup vs baseline: 2.1559x; 2.1559x over previous
//
#include <hip/hip_runtime.h>
#include <hip/hip_fp8.h>
#include <math.h>

#define TAU 32.0f
#define LO_SCALE 2048.0f
#define INV_LO_SCALE (1.0f/2048.0f)

typedef _Float16 f16x8 __attribute__((ext_vector_type(8)));
typedef float    f32x16 __attribute__((ext_vector_type(16)));

#if defined(__has_builtin)
#if __has_builtin(__builtin_amdgcn_cvt_f32_fp8) && __has_builtin(__builtin_amdgcn_cvt_pk_fp8_f32)
#define HAVE_FP8_BUILTINS 1
#endif
#endif

static __device__ __forceinline__ unsigned char enc_e4m3(float x) {
#ifdef HAVE_FP8_BUILTINS
    int p = __builtin_amdgcn_cvt_pk_fp8_f32(x, x, 0, false);
    return (unsigned char)(p & 0xff);
#else
    __hip_fp8_e4m3 q(x);
    return (unsigned char)q.__x;
#endif
}

#ifdef HAVE_FP8_BUILTINS
#define DEC_E4M3(W, SEL) __builtin_amdgcn_cvt_f32_fp8((int)(W), (SEL))
#else
static __device__ __forceinline__ float dec_e4m3_sw(unsigned w, int sel) {
    __hip_fp8_e4m3 q; q.__x = (unsigned char)((w >> (8 * sel)) & 0xff);
    return (float)q;
}
#define DEC_E4M3(W, SEL) dec_e4m3_sw((W), (SEL))
#endif

// ---------------------------------------------------------------------------
// Kernel 1 (v3): MW[n][k] = sum_e M[n%90][e] * W[e][k], packed fragment order.
// R7's version was latency-bound (280us profiled, VGPR=20: dependent chains of
// 768 stride-3072B loads/thread at 9% occupancy). v3 stages W through LDS in
// 16-row chunks, double-buffered, coalesced float4 loads issued 1 chunk ahead;
// compute is LDS-throughput-bound (stride-1 reads, conflict-free) + Ml
// broadcast. One barrier per chunk.
// Output layout (unchanged, feeds fused kernel's coalesced B loads):
//   frag = (k/16)*6 + n/32 ; lane = ((k>>3)&1)*32 + (n&31), j = k&7
//   PBhi[frag*512 + lane*8 + j] (f16), PBlo[...] (e4m3 of lo*2048)
// ws: 192*768*2B + 192*768*1B = 442,368 B (fits proven 552,960).
// ---------------------------------------------------------------------------
__global__ __launch_bounds__(256) void precompute_mw_packed(
    const float* __restrict__ Wt, const float* __restrict__ Wd,
    const float* __restrict__ dmem, _Float16* __restrict__ PBhi,
    unsigned char* __restrict__ PBlo)
{
    __shared__ float Ml[3 * 768];          // 9 KB
    __shared__ float WL[2][16 * 256];      // 32 KB double-buffered W chunks
    const int nt  = blockIdx.x;   // 0..63 -> rows 3nt..3nt+2 of 192
    const int kc  = blockIdx.y;   // 0..2
    const int n0  = nt * 3;
    const int tid = threadIdx.x;
    const int k   = kc * 256 + tid;
    float v[3] = {0.f, 0.f, 0.f};
    if (n0 < 180) {               // block-uniform (barriers inside are safe)
        const float* __restrict__ W = (n0 < 90) ? Wt : Wd;
        const int m0 = (n0 < 90) ? n0 : n0 - 90;
        for (int idx = tid; idx < 3 * 768; idx += 256)
            Ml[idx] = dmem[m0 * 768 + idx];

        const int sr   = tid >> 6;         // staging base row 0..3
        const int scol = (tid & 63) * 4;   // staging float4 column
        const float* __restrict__ Wbase = W + kc * 256 + scol;

        float4 pre[4];
        #pragma unroll
        for (int i = 0; i < 4; ++i)        // prologue: chunk 0
            pre[i] = *(const float4*)(Wbase + (sr + 4 * i) * 768);
        #pragma unroll
        for (int i = 0; i < 4; ++i)
            *(float4*)(&WL[0][(sr + 4 * i) * 256 + scol]) = pre[i];

        float a0 = 0.f, a1 = 0.f, a2 = 0.f;
        for (int c = 0; c < 48; ++c) {
            if (c < 47) {                  // issue next chunk's loads early
                #pragma unroll
                for (int i = 0; i < 4; ++i)
                    pre[i] = *(const float4*)(Wbase + ((c + 1) * 16 + sr + 4 * i) * 768);
            }
            __syncthreads();  // (a) WL[c&1] stores visible, (b) WL[(c+1)&1] reads done
            const float* __restrict__ wl = &WL[c & 1][tid];
            const float* __restrict__ ml = Ml + c * 16;
            #pragma unroll
            for (int e = 0; e < 16; ++e) {
                const float w = wl[e * 256];       // stride-1 across tid: no conflicts
                a0 = fmaf(ml[e],        w, a0);    // LDS broadcast
                a1 = fmaf(ml[768 + e],  w, a1);
                a2 = fmaf(ml[1536 + e], w, a2);
            }
            if (c < 47) {
                #pragma unroll
                for (int i = 0; i < 4; ++i)
                    *(float4*)(&WL[(c + 1) & 1][(sr + 4 * i) * 256 + scol]) = pre[i];
            }
        }
        v[0] = a0; v[1] = a1; v[2] = a2;
    }
    const int t = k >> 5, ks = (k >> 4) & 1, h = (k >> 3) & 1, j = k & 7;
    const int fragc = (t * 2 + ks) * 6;
    #pragma unroll
    for (int i = 0; i < 3; ++i) {
        const int n = n0 + i;
        const int idx = (fragc + (n >> 5)) * 512 + (h * 32 + (n & 31)) * 8 + j;
        _Float16 hi = (_Float16)v[i];
        float lo = (v[i] - (float)hi) * LO_SCALE;
        PBhi[idx] = hi;
        PBlo[idx] = enc_e4m3(lo);
    }
}

// ---------------------------------------------------------------------------
// Kernel 2: split-precision MFMA GEMM (f16 hi/hi + cross terms w/ fp8 B-lo)
// + fused softmax chain. Unchanged from round 7 (packed coalesced B,
// 1-ksub-deep B ping-pong prefetch, single A buffer, 58.6 KB LDS).
// ---------------------------------------------------------------------------
#define MFMA_BODY(KS, BH, BL) do {                                          \
    const int _ao = (arow * 64 + (KS) * 32 + asel) ^ swzA;                  \
    f16x8 _ah = *(const f16x8*)((const char*)AhL + _ao);                    \
    f16x8 _al = *(const f16x8*)((const char*)AlL + _ao);                    \
    _Pragma("unroll")                                                       \
    for (int _nt = 0; _nt < 3; ++_nt) {                                     \
        f16x8 _bl;                                                          \
        _bl[0] = (_Float16)DEC_E4M3(BL[_nt].x, 0);                          \
        _bl[1] = (_Float16)DEC_E4M3(BL[_nt].x, 1);                          \
        _bl[2] = (_Float16)DEC_E4M3(BL[_nt].x, 2);                          \
        _bl[3] = (_Float16)DEC_E4M3(BL[_nt].x, 3);                          \
        _bl[4] = (_Float16)DEC_E4M3(BL[_nt].y, 0);                          \
        _bl[5] = (_Float16)DEC_E4M3(BL[_nt].y, 1);                          \
        _bl[6] = (_Float16)DEC_E4M3(BL[_nt].y, 2);                          \
        _bl[7] = (_Float16)DEC_E4M3(BL[_nt].y, 3);                          \
        acc1[_nt] = __builtin_amdgcn_mfma_f32_32x32x16_f16(_ah, BH[_nt], acc1[_nt], 0, 0, 0); \
        acc2[_nt] = __builtin_amdgcn_mfma_f32_32x32x16_f16(_ah, _bl,     acc2[_nt], 0, 0, 0); \
        acc2[_nt] = __builtin_amdgcn_mfma_f32_32x32x16_f16(_al, BH[_nt], acc2[_nt], 0, 0, 0); \
    }                                                                       \
} while (0)

__global__ __launch_bounds__(256, 1) void fused_memnet(
    const float* __restrict__ F, const _Float16* __restrict__ PBhi,
    const unsigned char* __restrict__ PBlo, float* __restrict__ out)
{
    __shared__ alignas(16) _Float16 AhL[64 * 32];   // 4 KB swizzled
    __shared__ alignas(16) _Float16 AlL[64 * 32];   // 4 KB
    __shared__ float raw[64 * 196];                 // 50.2 KB epilogue
    __shared__ float ss[64];

    const int tid  = threadIdx.x;
    const int lane = tid & 63;
    const int wid  = tid >> 6;
    const int wrow = (wid >> 1) * 32;
    const int wcol = (wid & 1) * 96;
    const int row0 = blockIdx.x * 64;

    // A staging ids
    const int srow = tid >> 2;
    const int sc   = tid & 3;
    const float* __restrict__ Fp = F + (row0 + srow) * 768 + sc * 8;
    const int wb = (srow * 64 + sc * 16) ^ ((srow & 7) << 4);

    // packed-B per-lane bases (coalesced: 64 lanes x 16B hi / 8B lo contiguous)
    const _Float16*      __restrict__ pbh = PBhi + (wid & 1) * 3 * 512 + lane * 8;
    const unsigned char* __restrict__ pbl = PBlo + (wid & 1) * 3 * 512 + lane * 8;

    // A fragment read addressing
    const int arow = wrow + (lane & 31);
    const int swzA = (arow & 7) << 4;
    const int asel = (lane >> 5) * 16;

    f32x16 acc1[3], acc2[3];
    #pragma unroll
    for (int nt = 0; nt < 3; ++nt)
        #pragma unroll
        for (int r = 0; r < 16; ++r) { acc1[nt][r] = 0.f; acc2[nt][r] = 0.f; }

    float ps = 0.f;
    float4 p0 = *(const float4*)(Fp);
    float4 p1 = *(const float4*)(Fp + 4);

    f16x8 Bh0[3], Bh1[3];
    uint2 Bl0[3], Bl1[3];
    #pragma unroll
    for (int nt = 0; nt < 3; ++nt) {            // preload ksub_lin = 0
        Bh0[nt] = *(const f16x8*)(pbh + nt * 512);
        Bl0[nt] = *(const uint2*)(pbl + nt * 512);
    }

    for (int t = 0; t < 24; ++t) {
        __syncthreads();                        // window t-1 LDS reads done
        {   // convert & store A window t, accumulate sumsq
            f16x8 h8, l8;
            float xs[8] = {p0.x, p0.y, p0.z, p0.w, p1.x, p1.y, p1.z, p1.w};
            #pragma unroll
            for (int i = 0; i < 8; ++i) {
                float x = xs[i];
                _Float16 hh = (_Float16)x;
                h8[i] = hh;
                l8[i] = (_Float16)((x - (float)hh) * LO_SCALE);
                ps += x * x;
            }
            *(f16x8*)((char*)AhL + wb) = h8;
            *(f16x8*)((char*)AlL + wb) = l8;
        }
        if (t < 23) {                           // F prefetch (1 window deep)
            p0 = *(const float4*)(Fp + (t + 1) * 32);
            p1 = *(const float4*)(Fp + (t + 1) * 32 + 4);
        }
        __syncthreads();                        // window t A visible

        // ksub 0 (kl=2t): prefetch kl=2t+1 into slot1, MFMA slot0
        #pragma unroll
        for (int nt = 0; nt < 3; ++nt) {
            Bh1[nt] = *(const f16x8*)(pbh + (2 * t + 1) * 3072 + nt * 512);
            Bl1[nt] = *(const uint2*)(pbl + (2 * t + 1) * 3072 + nt * 512);
        }
        MFMA_BODY(0, Bh0, Bl0);
        // ksub 1 (kl=2t+1): prefetch kl=2t+2 into slot0, MFMA slot1
        if (t < 23) {
            #pragma unroll
            for (int nt = 0; nt < 3; ++nt) {
                Bh0[nt] = *(const f16x8*)(pbh + (2 * t + 2) * 3072 + nt * 512);
                Bl0[nt] = *(const uint2*)(pbl + (2 * t + 2) * 3072 + nt * 512);
            }
        }
        MFMA_BODY(1, Bh1, Bl1);
    }

    // ---- row sum-of-squares: 4 staging threads per row
    ps += __shfl_xor(ps, 1);
    ps += __shfl_xor(ps, 2);
    if (sc == 0) ss[srow] = ps;

    // ---- write raw scores (verified 32x32 C/D layout:
    //      col=lane&31, row=(reg&3)+8*(reg>>2)+4*(lane>>5))
    #pragma unroll
    for (int nt = 0; nt < 3; ++nt) {
        const int cl = wcol + nt * 32 + (lane & 31);
        #pragma unroll
        for (int r = 0; r < 16; ++r) {
            const int rl = wrow + (r & 3) + 8 * (r >> 2) + 4 * (lane >> 5);
            raw[rl * 196 + cl] = acc1[nt][r] + acc2[nt][r] * INV_LO_SCALE;
        }
    }
    __syncthreads();

    // ---- softmax chain, one thread per row
    if (tid < 64) {
        const int r = tid;
        const float s = TAU / sqrtf(ss[r]);       // TAU / ||f||
        const float* Sr = raw + r * 196;
        float logit[9];
        #pragma unroll
        for (int d = 0; d < 9; ++d) {
            float vv[10];
            float mx = -1e30f;
            #pragma unroll
            for (int m = 0; m < 10; ++m) {
                vv[m] = s * Sr[d * 10 + m];
                mx = fmaxf(mx, vv[m]);
            }
            float den = 0.f, num = 0.f;
            #pragma unroll
            for (int m = 0; m < 10; ++m) {
                const float e = expf(vv[m] - mx);
                den += e;
                num = fmaf(e, Sr[90 + d * 10 + m], num);
            }
            logit[d] = s * num / den;             // TAU * (sep_emb . q_dom)
        }
        float mx2 = -1e30f;
        #pragma unroll
        for (int d = 0; d < 9; ++d) mx2 = fmaxf(mx2, logit[d]);
        float e2[9], den2 = 0.f;
        #pragma unroll
        for (int d = 0; d < 9; ++d) { e2[d] = expf(logit[d] - mx2); den2 += e2[d]; }
        const float inv = 1.f / den2;
        float* op = out + (row0 + r) * 9;
        #pragma unroll
        for (int d = 0; d < 9; ++d) op[d] = e2[d] * inv;
    }
}

// ---------------------------------------------------------------------------
extern "C" void kernel_launch(void* const* d_in, const int* in_sizes, int n_in,
                              void* d_out, int out_size, void* d_ws, size_t ws_size,
                              hipStream_t stream)
{
    const float* feature = (const float*)d_in[0];
    // d_in[1] = category (int64) — unused by the reference computation
    const float* Wt   = (const float*)d_in[2];
    const float* Wd   = (const float*)d_in[3];
    const float* dmem = (const float*)d_in[4];
    float* outp = (float*)d_out;
    _Float16* PBhi = (_Float16*)d_ws;                           // 294,912 B
    unsigned char* PBlo = (unsigned char*)d_ws + 192 * 768 * 2; // 147,456 B

    precompute_mw_packed<<<dim3(64, 3), 256, 0, stream>>>(Wt, Wd, dmem, PBhi, PBlo);
    fused_memnet<<<32768 / 64, 256, 0, stream>>>(feature, PBhi, PBlo, outp);
}

// Round 9
// 59.881 us; speedup vs baseline: 3.8475x; 1.7846x over previous
//
#include <hip/hip_runtime.h>
#include <hip/hip_fp8.h>
#include <math.h>

#define TAU 32.0f
#define LO_SCALE 2048.0f
#define INV_LO_SCALE (1.0f/2048.0f)

typedef _Float16 f16x8 __attribute__((ext_vector_type(8)));
typedef float    f32x16 __attribute__((ext_vector_type(16)));

#if defined(__has_builtin)
#if __has_builtin(__builtin_amdgcn_cvt_f32_fp8) && __has_builtin(__builtin_amdgcn_cvt_pk_fp8_f32)
#define HAVE_FP8_BUILTINS 1
#endif
#endif

static __device__ __forceinline__ unsigned char enc_e4m3(float x) {
#ifdef HAVE_FP8_BUILTINS
    int p = __builtin_amdgcn_cvt_pk_fp8_f32(x, x, 0, false);
    return (unsigned char)(p & 0xff);
#else
    __hip_fp8_e4m3 q(x);
    return (unsigned char)q.__x;
#endif
}

#ifdef HAVE_FP8_BUILTINS
#define DEC_E4M3(W, SEL) __builtin_amdgcn_cvt_f32_fp8((int)(W), (SEL))
#else
static __device__ __forceinline__ float dec_e4m3_sw(unsigned w, int sel) {
    __hip_fp8_e4m3 q; q.__x = (unsigned char)((w >> (8 * sel)) & 0xff);
    return (float)q;
}
#define DEC_E4M3(W, SEL) dec_e4m3_sw((W), (SEL))
#endif

// ---------------------------------------------------------------------------
// Kernel 1 (v4): MW[n][k] = sum_e M[n%90][e] * W[e][k], packed fragment order.
// R8's v3 was 70us at 1 wave/SIMD (192 blocks x 4 waves): LDS-chunk pipeline
// latency fully exposed. v4: 1024-thread blocks, e-dim split across 4
// quarters of 256 threads; W read DIRECTLY from global coalesced (L2-resident,
// 147 MB total / 34.5 TB/s ~ 4.3us), M via LDS float4 broadcast, 4-way LDS
// reduction at the end. 16 waves/CU = 4/SIMD, 8 loads in flight/thread.
// Output layout (unchanged, feeds fused kernel's coalesced B loads):
//   frag = (k/16)*6 + n/32 ; lane = ((k>>3)&1)*32 + (n&31), j = k&7
//   PBhi[frag*512 + lane*8 + j] (f16), PBlo[...] (e4m3 of lo*2048)
// ws: 192*768*2B + 192*768*1B = 442,368 B (fits proven 552,960).
// ---------------------------------------------------------------------------
__global__ __launch_bounds__(1024) void precompute_mw_packed(
    const float* __restrict__ Wt, const float* __restrict__ Wd,
    const float* __restrict__ dmem, _Float16* __restrict__ PBhi,
    unsigned char* __restrict__ PBlo)
{
    __shared__ float Ml[3 * 768];          // 9 KB
    __shared__ float red[3][4][256];       // 12 KB quarter-partial reduce
    const int nt  = blockIdx.x;   // 0..63 -> rows 3nt..3nt+2 of 192
    const int kc  = blockIdx.y;   // 0..2
    const int n0  = nt * 3;
    const int tid = threadIdx.x;
    const int q   = tid >> 8;     // e-quarter 0..3
    const int kl  = tid & 255;    // k within chunk
    const int k   = kc * 256 + kl;
    float v[3] = {0.f, 0.f, 0.f};
    if (n0 < 180) {               // block-uniform (barriers inside are safe)
        const float* __restrict__ W = (n0 < 90) ? Wt : Wd;
        const int m0 = (n0 < 90) ? n0 : n0 - 90;
        for (int idx = tid; idx < 3 * 768; idx += 1024)
            Ml[idx] = dmem[m0 * 768 + idx];
        __syncthreads();

        const float* __restrict__ Wq  = W + (q * 192) * 768 + k;
        const float* __restrict__ mlb = Ml + q * 192;
        float a0 = 0.f, a1 = 0.f, a2 = 0.f;
        for (int e0 = 0; e0 < 192; e0 += 8) {
            float w[8];
            #pragma unroll
            for (int i = 0; i < 8; ++i)          // 8 independent coalesced loads
                w[i] = Wq[(e0 + i) * 768];
            float4 m0a = *(const float4*)(mlb + e0);
            float4 m0b = *(const float4*)(mlb + e0 + 4);
            float4 m1a = *(const float4*)(mlb + 768 + e0);
            float4 m1b = *(const float4*)(mlb + 768 + e0 + 4);
            float4 m2a = *(const float4*)(mlb + 1536 + e0);
            float4 m2b = *(const float4*)(mlb + 1536 + e0 + 4);
            a0 = fmaf(m0a.x, w[0], a0); a0 = fmaf(m0a.y, w[1], a0);
            a0 = fmaf(m0a.z, w[2], a0); a0 = fmaf(m0a.w, w[3], a0);
            a0 = fmaf(m0b.x, w[4], a0); a0 = fmaf(m0b.y, w[5], a0);
            a0 = fmaf(m0b.z, w[6], a0); a0 = fmaf(m0b.w, w[7], a0);
            a1 = fmaf(m1a.x, w[0], a1); a1 = fmaf(m1a.y, w[1], a1);
            a1 = fmaf(m1a.z, w[2], a1); a1 = fmaf(m1a.w, w[3], a1);
            a1 = fmaf(m1b.x, w[4], a1); a1 = fmaf(m1b.y, w[5], a1);
            a1 = fmaf(m1b.z, w[6], a1); a1 = fmaf(m1b.w, w[7], a1);
            a2 = fmaf(m2a.x, w[0], a2); a2 = fmaf(m2a.y, w[1], a2);
            a2 = fmaf(m2a.z, w[2], a2); a2 = fmaf(m2a.w, w[3], a2);
            a2 = fmaf(m2b.x, w[4], a2); a2 = fmaf(m2b.y, w[5], a2);
            a2 = fmaf(m2b.z, w[6], a2); a2 = fmaf(m2b.w, w[7], a2);
        }
        red[0][q][kl] = a0;
        red[1][q][kl] = a1;
        red[2][q][kl] = a2;
        __syncthreads();
        if (q == 0) {
            #pragma unroll
            for (int i = 0; i < 3; ++i)
                v[i] = red[i][0][kl] + red[i][1][kl] + red[i][2][kl] + red[i][3][kl];
        }
    }
    if (q == 0) {
        const int t = k >> 5, ks = (k >> 4) & 1, h = (k >> 3) & 1, j = k & 7;
        const int fragc = (t * 2 + ks) * 6;
        #pragma unroll
        for (int i = 0; i < 3; ++i) {
            const int n = n0 + i;
            const int idx = (fragc + (n >> 5)) * 512 + (h * 32 + (n & 31)) * 8 + j;
            _Float16 hi = (_Float16)v[i];
            float lo = (v[i] - (float)hi) * LO_SCALE;
            PBhi[idx] = hi;
            PBlo[idx] = enc_e4m3(lo);
        }
    }
}

// ---------------------------------------------------------------------------
// Kernel 2: split-precision MFMA GEMM (f16 hi/hi + cross terms w/ fp8 B-lo)
// + fused softmax chain. Unchanged from round 8 (packed coalesced B,
// 1-ksub-deep B ping-pong prefetch, single A buffer, 58.6 KB LDS).
// ---------------------------------------------------------------------------
#define MFMA_BODY(KS, BH, BL) do {                                          \
    const int _ao = (arow * 64 + (KS) * 32 + asel) ^ swzA;                  \
    f16x8 _ah = *(const f16x8*)((const char*)AhL + _ao);                    \
    f16x8 _al = *(const f16x8*)((const char*)AlL + _ao);                    \
    _Pragma("unroll")                                                       \
    for (int _nt = 0; _nt < 3; ++_nt) {                                     \
        f16x8 _bl;                                                          \
        _bl[0] = (_Float16)DEC_E4M3(BL[_nt].x, 0);                          \
        _bl[1] = (_Float16)DEC_E4M3(BL[_nt].x, 1);                          \
        _bl[2] = (_Float16)DEC_E4M3(BL[_nt].x, 2);                          \
        _bl[3] = (_Float16)DEC_E4M3(BL[_nt].x, 3);                          \
        _bl[4] = (_Float16)DEC_E4M3(BL[_nt].y, 0);                          \
        _bl[5] = (_Float16)DEC_E4M3(BL[_nt].y, 1);                          \
        _bl[6] = (_Float16)DEC_E4M3(BL[_nt].y, 2);                          \
        _bl[7] = (_Float16)DEC_E4M3(BL[_nt].y, 3);                          \
        acc1[_nt] = __builtin_amdgcn_mfma_f32_32x32x16_f16(_ah, BH[_nt], acc1[_nt], 0, 0, 0); \
        acc2[_nt] = __builtin_amdgcn_mfma_f32_32x32x16_f16(_ah, _bl,     acc2[_nt], 0, 0, 0); \
        acc2[_nt] = __builtin_amdgcn_mfma_f32_32x32x16_f16(_al, BH[_nt], acc2[_nt], 0, 0, 0); \
    }                                                                       \
} while (0)

__global__ __launch_bounds__(256, 1) void fused_memnet(
    const float* __restrict__ F, const _Float16* __restrict__ PBhi,
    const unsigned char* __restrict__ PBlo, float* __restrict__ out)
{
    __shared__ alignas(16) _Float16 AhL[64 * 32];   // 4 KB swizzled
    __shared__ alignas(16) _Float16 AlL[64 * 32];   // 4 KB
    __shared__ float raw[64 * 196];                 // 50.2 KB epilogue
    __shared__ float ss[64];

    const int tid  = threadIdx.x;
    const int lane = tid & 63;
    const int wid  = tid >> 6;
    const int wrow = (wid >> 1) * 32;
    const int wcol = (wid & 1) * 96;
    const int row0 = blockIdx.x * 64;

    // A staging ids
    const int srow = tid >> 2;
    const int sc   = tid & 3;
    const float* __restrict__ Fp = F + (row0 + srow) * 768 + sc * 8;
    const int wb = (srow * 64 + sc * 16) ^ ((srow & 7) << 4);

    // packed-B per-lane bases (coalesced: 64 lanes x 16B hi / 8B lo contiguous)
    const _Float16*      __restrict__ pbh = PBhi + (wid & 1) * 3 * 512 + lane * 8;
    const unsigned char* __restrict__ pbl = PBlo + (wid & 1) * 3 * 512 + lane * 8;

    // A fragment read addressing
    const int arow = wrow + (lane & 31);
    const int swzA = (arow & 7) << 4;
    const int asel = (lane >> 5) * 16;

    f32x16 acc1[3], acc2[3];
    #pragma unroll
    for (int nt = 0; nt < 3; ++nt)
        #pragma unroll
        for (int r = 0; r < 16; ++r) { acc1[nt][r] = 0.f; acc2[nt][r] = 0.f; }

    float ps = 0.f;
    float4 p0 = *(const float4*)(Fp);
    float4 p1 = *(const float4*)(Fp + 4);

    f16x8 Bh0[3], Bh1[3];
    uint2 Bl0[3], Bl1[3];
    #pragma unroll
    for (int nt = 0; nt < 3; ++nt) {            // preload ksub_lin = 0
        Bh0[nt] = *(const f16x8*)(pbh + nt * 512);
        Bl0[nt] = *(const uint2*)(pbl + nt * 512);
    }

    for (int t = 0; t < 24; ++t) {
        __syncthreads();                        // window t-1 LDS reads done
        {   // convert & store A window t, accumulate sumsq
            f16x8 h8, l8;
            float xs[8] = {p0.x, p0.y, p0.z, p0.w, p1.x, p1.y, p1.z, p1.w};
            #pragma unroll
            for (int i = 0; i < 8; ++i) {
                float x = xs[i];
                _Float16 hh = (_Float16)x;
                h8[i] = hh;
                l8[i] = (_Float16)((x - (float)hh) * LO_SCALE);
                ps += x * x;
            }
            *(f16x8*)((char*)AhL + wb) = h8;
            *(f16x8*)((char*)AlL + wb) = l8;
        }
        if (t < 23) {                           // F prefetch (1 window deep)
            p0 = *(const float4*)(Fp + (t + 1) * 32);
            p1 = *(const float4*)(Fp + (t + 1) * 32 + 4);
        }
        __syncthreads();                        // window t A visible

        // ksub 0 (kl=2t): prefetch kl=2t+1 into slot1, MFMA slot0
        #pragma unroll
        for (int nt = 0; nt < 3; ++nt) {
            Bh1[nt] = *(const f16x8*)(pbh + (2 * t + 1) * 3072 + nt * 512);
            Bl1[nt] = *(const uint2*)(pbl + (2 * t + 1) * 3072 + nt * 512);
        }
        MFMA_BODY(0, Bh0, Bl0);
        // ksub 1 (kl=2t+1): prefetch kl=2t+2 into slot0, MFMA slot1
        if (t < 23) {
            #pragma unroll
            for (int nt = 0; nt < 3; ++nt) {
                Bh0[nt] = *(const f16x8*)(pbh + (2 * t + 2) * 3072 + nt * 512);
                Bl0[nt] = *(const uint2*)(pbl + (2 * t + 2) * 3072 + nt * 512);
            }
        }
        MFMA_BODY(1, Bh1, Bl1);
    }

    // ---- row sum-of-squares: 4 staging threads per row
    ps += __shfl_xor(ps, 1);
    ps += __shfl_xor(ps, 2);
    if (sc == 0) ss[srow] = ps;

    // ---- write raw scores (verified 32x32 C/D layout:
    //      col=lane&31, row=(reg&3)+8*(reg>>2)+4*(lane>>5))
    #pragma unroll
    for (int nt = 0; nt < 3; ++nt) {
        const int cl = wcol + nt * 32 + (lane & 31);
        #pragma unroll
        for (int r = 0; r < 16; ++r) {
            const int rl = wrow + (r & 3) + 8 * (r >> 2) + 4 * (lane >> 5);
            raw[rl * 196 + cl] = acc1[nt][r] + acc2[nt][r] * INV_LO_SCALE;
        }
    }
    __syncthreads();

    // ---- softmax chain, one thread per row
    if (tid < 64) {
        const int r = tid;
        const float s = TAU / sqrtf(ss[r]);       // TAU / ||f||
        const float* Sr = raw + r * 196;
        float logit[9];
        #pragma unroll
        for (int d = 0; d < 9; ++d) {
            float vv[10];
            float mx = -1e30f;
            #pragma unroll
            for (int m = 0; m < 10; ++m) {
                vv[m] = s * Sr[d * 10 + m];
                mx = fmaxf(mx, vv[m]);
            }
            float den = 0.f, num = 0.f;
            #pragma unroll
            for (int m = 0; m < 10; ++m) {
                const float e = expf(vv[m] - mx);
                den += e;
                num = fmaf(e, Sr[90 + d * 10 + m], num);
            }
            logit[d] = s * num / den;             // TAU * (sep_emb . q_dom)
        }
        float mx2 = -1e30f;
        #pragma unroll
        for (int d = 0; d < 9; ++d) mx2 = fmaxf(mx2, logit[d]);
        float e2[9], den2 = 0.f;
        #pragma unroll
        for (int d = 0; d < 9; ++d) { e2[d] = expf(logit[d] - mx2); den2 += e2[d]; }
        const float inv = 1.f / den2;
        float* op = out + (row0 + r) * 9;
        #pragma unroll
        for (int d = 0; d < 9; ++d) op[d] = e2[d] * inv;
    }
}

// ---------------------------------------------------------------------------
extern "C" void kernel_launch(void* const* d_in, const int* in_sizes, int n_in,
                              void* d_out, int out_size, void* d_ws, size_t ws_size,
                              hipStream_t stream)
{
    const float* feature = (const float*)d_in[0];
    // d_in[1] = category (int64) — unused by the reference computation
    const float* Wt   = (const float*)d_in[2];
    const float* Wd   = (const float*)d_in[3];
    const float* dmem = (const float*)d_in[4];
    float* outp = (float*)d_out;
    _Float16* PBhi = (_Float16*)d_ws;                           // 294,912 B
    unsigned char* PBlo = (unsigned char*)d_ws + 192 * 768 * 2; // 147,456 B

    precompute_mw_packed<<<dim3(64, 3), 1024, 0, stream>>>(Wt, Wd, dmem, PBhi, PBlo);
    fused_memnet<<<32768 / 64, 256, 0, stream>>>(feature, PBhi, PBlo, outp);
}